// Round 1
// baseline (2234.279 us; speedup 1.0000x reference)
//
#include <hip/hip_runtime.h>

#define SEQ  128
#define B_   512
#define IN_  512
#define HID_ 512
#define KTOT 1536          // 512 x | 512 m_hi | 512 m_lo
#define NTOT 4096          // (h/16)*128 + k*16 + (h%16)
#define BM   64
#define BN   128
#define BK   64
#define NKT  (KTOT/BK)     // 24

typedef _Float16 f16;
typedef _Float16 f16x8 __attribute__((ext_vector_type(8)));
typedef _Float16 f16x4 __attribute__((ext_vector_type(4)));
typedef float    f32x4 __attribute__((ext_vector_type(4)));

// ws layout (bytes): total 82,837,504 needed
#define OFF_BT  0u           // [4096][1536] f16 = 12,582,912
#define OFF_X16 12582912u    // [128][512][512] f16 = 67,108,864
#define OFF_C   79691776u    // [512][512] f32 = 1,048,576
#define OFF_MH  80740352u    // [2][512*512] f16 = 1,048,576
#define OFF_ML  81788928u    // [2][512*512] f16 = 1,048,576

__device__ __forceinline__ void gll16(const void* g, void* l) {
  __builtin_amdgcn_global_load_lds(
      (const __attribute__((address_space(1))) unsigned int*)g,
      (__attribute__((address_space(3))) unsigned int*)l,
      16, 0, 0);
}

__device__ __forceinline__ float sigm_f(float x) {
  return __fdividef(1.f, 1.f + __expf(-x));
}
__device__ __forceinline__ float tanh_f(float x) {
  x = fminf(fmaxf(x, -15.f), 15.f);
  float u = __expf(2.f * x);
  return __fdividef(u - 1.f, u + 1.f);
}

// ---- one-time prep kernels ------------------------------------------------

// B^T[n][r], n = ht*128 + k*16 + hl (h = ht*16+hl):
//   r<512: W_ih[k][r][h]; 512<=r<1024: W_hh[k][r-512][h]; else W_hh[k][r-1024][h]
__global__ void build_bt(const float* __restrict__ wih,
                         const float* __restrict__ whh,
                         f16* __restrict__ bt) {
  int n  = blockIdx.x;
  int hl = n & 15, k = (n >> 4) & 7, ht = n >> 7;
  int h  = ht * 16 + hl;
  const float* pih = wih + (size_t)k * IN_ * HID_ + h;
  const float* phh = whh + (size_t)k * HID_ * HID_ + h;
  f16* dst = bt + (size_t)n * KTOT;
  for (int r = threadIdx.x; r < 512; r += 256) {
    float a = pih[(size_t)r * HID_];
    float b = phh[(size_t)r * HID_];
    dst[r]        = (f16)a;
    dst[512 + r]  = (f16)b;
    dst[1024 + r] = (f16)b;
  }
}

__global__ void cvt_x(const float4* __restrict__ x, f16x4* __restrict__ y, int nvec) {
  int i = blockIdx.x * blockDim.x + threadIdx.x;
  int stride = gridDim.x * blockDim.x;
  for (; i < nvec; i += stride) {
    float4 v = x[i];
    f16x4 o = { (f16)v.x, (f16)v.y, (f16)v.z, (f16)v.w };
    y[i] = o;
  }
}

__global__ void init_state(float* __restrict__ c, f16* __restrict__ mh, f16* __restrict__ ml) {
  int i = blockIdx.x * blockDim.x + threadIdx.x;   // grid 1024x256 = 262144
  c[i]  = 1.f;
  mh[i] = (f16)1.f;
  ml[i] = (f16)0.f;
}

// ---- per-step fused GEMM + cell ------------------------------------------
// grid (32 n-tiles, 8 m-tiles), 256 threads (4 waves), wave tile 16(M)x128(N)
__global__ __launch_bounds__(256)
void nas_step(const f16* __restrict__ xt,     // [512][512] f16, step t
              const f16* __restrict__ bt,     // [4096][1536] f16
              const f16* __restrict__ mh_in,
              const f16* __restrict__ ml_in,
              f16* __restrict__ mh_out,
              f16* __restrict__ ml_out,
              float* __restrict__ cst,        // [512][512] f32, in-place
              float* __restrict__ out,        // d_out (written only if last)
              int last) {
  __shared__ char lds[49152];                 // A[2][8192] | B[2][16384]
  char* Abase = lds;
  char* Bbase = lds + 16384;

  const int tid  = threadIdx.x;
  const int lane = tid & 63;
  const int wid  = tid >> 6;
  const int nt   = blockIdx.x;                // 0..31
  const int mt   = blockIdx.y;                // 0..7

  const f16* asrc[3] = { xt, mh_in, ml_in };

  // stage A tile [64][64] f16 (8KB): linear LDS dest, inverse-swizzled source.
  // logical (r,c) lives at phys byte r*128 + ((2c) ^ ((r&7)<<4))
  auto stageA = [&](int buf, int kt) {
    const f16* src = asrc[kt >> 3];
    int kofs = (kt & 7) * BK;
#pragma unroll
    for (int p = 0; p < 2; ++p) {
      int u = p * 256 + tid;                  // 16B chunk id, 0..511
      int r = u >> 3;
      int c16 = (u & 7) ^ (r & 7);            // inverse swizzle on source
      gll16(src + ((size_t)(mt * BM + r) << 9) + kofs + c16 * 8,
            Abase + buf * 8192 + (p * 256 + wid * 64) * 16);
    }
  };
  // stage B tile [128][64] f16 (16KB)
  auto stageB = [&](int buf, int kt) {
    int kg = kt * BK;
#pragma unroll
    for (int p = 0; p < 4; ++p) {
      int u = p * 256 + tid;                  // 0..1023
      int r = u >> 3;
      int c16 = (u & 7) ^ (r & 7);
      gll16(bt + (size_t)(nt * BN + r) * KTOT + kg + c16 * 8,
            Bbase + buf * 16384 + (p * 256 + wid * 64) * 16);
    }
  };

  f32x4 acc[8];
#pragma unroll
  for (int i = 0; i < 8; ++i) acc[i] = (f32x4){0.f, 0.f, 0.f, 0.f};

  stageA(0, 0); stageB(0, 0);
  __syncthreads();

  for (int kt = 0; kt < NKT; ++kt) {
    int cur = kt & 1;
    if (kt + 1 < NKT) { stageA(cur ^ 1, kt + 1); stageB(cur ^ 1, kt + 1); }
    const char* At = Abase + cur * 8192;
    const char* Bt = Bbase + cur * 16384;
#pragma unroll
    for (int kk = 0; kk < 2; ++kk) {
      int cb = (kk * 32 + ((lane >> 4) << 3)) * 2;     // byte col of 8-f16 frag
      int ra = wid * 16 + (lane & 15);
      f16x8 a = *(const f16x8*)(At + ra * 128 + (cb ^ ((ra & 7) << 4)));
#pragma unroll
      for (int ni = 0; ni < 8; ++ni) {
        int rb = ni * 16 + (lane & 15);
        f16x8 b = *(const f16x8*)(Bt + rb * 128 + (cb ^ ((rb & 7) << 4)));
        acc[ni] = __builtin_amdgcn_mfma_f32_16x16x32_f16(a, b, acc[ni], 0, 0, 0);
      }
    }
    __syncthreads();
  }

  // epilogue: lane holds all 8 gates for (b = mt*64+wid*16+(lane>>4)*4+q,
  //                                       h = nt*16+(lane&15)), q=0..3
  const int h = nt * 16 + (lane & 15);
  const int rb4 = (lane >> 4) << 2;
#pragma unroll
  for (int q = 0; q < 4; ++q) {
    int b = mt * 64 + wid * 16 + rb4 + q;
    size_t idx = ((size_t)b << 9) + h;
    float l10 = sigm_f(acc[0][q]);
    float l11 = fmaxf(acc[1][q], 0.f);
    float l12 = sigm_f(acc[2][q]);
    float l13 = fmaxf(acc[3][q], 0.f);
    float l14 = tanh_f(acc[4][q]);
    float l15 = sigm_f(acc[5][q]);
    float l16 = tanh_f(acc[6][q]);
    float l17 = sigm_f(acc[7][q]);
    float l20 = tanh_f(l10 * l11);
    float l21 = tanh_f(l12 + l13);
    float l22 = tanh_f(l14 * l15);
    float l23 = sigm_f(l16 + l17);
    float cn  = tanh_f(l20 + cst[idx]) * l21;
    float l31 = tanh_f(l22 + l23);
    float mn  = tanh_f(cn * l31);
    cst[idx] = cn;
    f16 mh = (f16)mn;
    mh_out[idx] = mh;
    ml_out[idx] = (f16)(mn - (float)mh);
    if (last) out[idx] = mn;
  }
}

// ---- host ----------------------------------------------------------------
extern "C" void kernel_launch(void* const* d_in, const int* in_sizes, int n_in,
                              void* d_out, int out_size, void* d_ws, size_t ws_size,
                              hipStream_t stream) {
  const float* inputs = (const float*)d_in[0];
  const float* wih    = (const float*)d_in[1];
  const float* whh    = (const float*)d_in[2];
  float* out = (float*)d_out;
  char* ws   = (char*)d_ws;

  f16*   BT  = (f16*)(ws + OFF_BT);
  f16*   X16 = (f16*)(ws + OFF_X16);
  float* C   = (float*)(ws + OFF_C);
  f16*   MH  = (f16*)(ws + OFF_MH);
  f16*   ML  = (f16*)(ws + OFF_ML);

  build_bt<<<NTOT, 256, 0, stream>>>(wih, whh, BT);
  cvt_x<<<2048, 256, 0, stream>>>((const float4*)inputs, (f16x4*)X16,
                                  SEQ * B_ * IN_ / 4);
  init_state<<<1024, 256, 0, stream>>>(C, MH, ML);

  for (int t = 0; t < SEQ; ++t) {
    int cur = t & 1;
    nas_step<<<dim3(32, 8), 256, 0, stream>>>(
        X16 + (size_t)t * B_ * IN_, BT,
        MH + (size_t)cur * (B_ * HID_), ML + (size_t)cur * (B_ * HID_),
        MH + (size_t)(cur ^ 1) * (B_ * HID_), ML + (size_t)(cur ^ 1) * (B_ * HID_),
        C, out, (t == SEQ - 1) ? 1 : 0);
  }
}